// Round 7
// baseline (1208.182 us; speedup 1.0000x reference)
//
#include <hip/hip_runtime.h>
#include <math.h>

#define T_TOK 2048
#define HD    2048
#define NEXP  64
#define KTOP  8
#define FD    768
#define CAPE  512

typedef float  f32x4 __attribute__((ext_vector_type(4)));
typedef __bf16 bf16x8 __attribute__((ext_vector_type(8)));
typedef __bf16 bf16x4 __attribute__((ext_vector_type(4)));
typedef __bf16 bf16x2 __attribute__((ext_vector_type(2)));

__device__ __forceinline__ void load_lds16(const void* g, void* l) {
  __builtin_amdgcn_global_load_lds(
      (const __attribute__((address_space(1))) unsigned int*)g,
      (__attribute__((address_space(3))) unsigned int*)l, 16, 0, 0);
}

#define WAITCNT(S) asm volatile(S ::: "memory")
#define PIN()      asm volatile("" ::: "memory")
#define BARRIER()  __builtin_amdgcn_s_barrier()

// ---------------- Kernel 1: router (4 tokens per block) + fused f32->bf16 ----------------
__global__ __launch_bounds__(256) void router_kernel(
    const float* __restrict__ x, const float* __restrict__ rw,
    int* __restrict__ cnt, int* __restrict__ tok_list, float* __restrict__ w_list,
    unsigned short* __restrict__ xb)
{
  const int t = threadIdx.x;
  const int tb = blockIdx.x * 4;
  __shared__ float xs[4][HD];
  __shared__ float lg[4][NEXP];

  const float4* xsrc = (const float4*)(x + (size_t)tb * HD);
  float4* xdst = (float4*)&xs[0][0];
  for (int i = t; i < 4 * HD / 4; i += 256) xdst[i] = xsrc[i];
  __syncthreads();

  {
    const int e = t >> 2, q = t & 3;
    const float* wrow = rw + (size_t)e * HD;
    float a0 = 0.f, a1 = 0.f, a2 = 0.f, a3 = 0.f;
    for (int i = 0; i < HD / 16; ++i) {
      int h = (i * 4 + q) * 4;
      float4 wv = *(const float4*)(wrow + h);
      float4 x0 = *(const float4*)&xs[0][h];
      float4 x1 = *(const float4*)&xs[1][h];
      float4 x2 = *(const float4*)&xs[2][h];
      float4 x3 = *(const float4*)&xs[3][h];
      a0 += wv.x*x0.x + wv.y*x0.y + wv.z*x0.z + wv.w*x0.w;
      a1 += wv.x*x1.x + wv.y*x1.y + wv.z*x1.z + wv.w*x1.w;
      a2 += wv.x*x2.x + wv.y*x2.y + wv.z*x2.z + wv.w*x2.w;
      a3 += wv.x*x3.x + wv.y*x3.y + wv.z*x3.z + wv.w*x3.w;
    }
    a0 += __shfl_xor(a0, 1); a0 += __shfl_xor(a0, 2);
    a1 += __shfl_xor(a1, 1); a1 += __shfl_xor(a1, 2);
    a2 += __shfl_xor(a2, 1); a2 += __shfl_xor(a2, 2);
    a3 += __shfl_xor(a3, 1); a3 += __shfl_xor(a3, 2);
    if (q == 0) { lg[0][e] = a0; lg[1][e] = a1; lg[2][e] = a2; lg[3][e] = a3; }
  }

  {
    const f32x4* xs4 = (const f32x4*)(x + (size_t)tb * HD);
    bf16x4* xbd = (bf16x4*)(xb + (size_t)tb * HD);
    #pragma unroll
    for (int j = 0; j < 8; ++j) {
      f32x4 v = xs4[j * 256 + t];
      xbd[j * 256 + t] = (bf16x4){(__bf16)v[0], (__bf16)v[1], (__bf16)v[2], (__bf16)v[3]};
    }
  }
  __syncthreads();

  const int wid = t >> 6, lane = t & 63;
  float v = lg[wid][lane];
  float mx = v;
  for (int o = 32; o; o >>= 1) mx = fmaxf(mx, __shfl_xor(mx, o));
  float p = expf(v - mx);
  float s = p;
  for (int o = 32; o; o >>= 1) s += __shfl_xor(s, o);
  float prob = p / s;

  float r = prob;
  float wk[KTOP]; int ik[KTOP]; float wsum = 0.f;
  #pragma unroll
  for (int k = 0; k < KTOP; ++k) {
    float bv = r; int bl = lane;
    for (int o = 32; o; o >>= 1) {
      float ov = __shfl_xor(bv, o); int ol = __shfl_xor(bl, o);
      if (ov > bv || (ov == bv && ol < bl)) { bv = ov; bl = ol; }
    }
    wk[k] = bv; ik[k] = bl; wsum += bv;
    if (lane == bl) r = -1.f;
  }
  if (lane == 0) {
    float inv = 1.f / (wsum + 1e-20f);
    int token = tb + wid;
    #pragma unroll
    for (int k = 0; k < KTOP; ++k) {
      int ex = ik[k];
      int pos = atomicAdd(&cnt[ex], 1);
      if (pos < CAPE) {
        tok_list[ex * CAPE + pos] = token;
        w_list[ex * CAPE + pos] = wk[k] * inv;
      }
    }
  }
}

// ============ GEMM blocks: M=256 tile, 512 threads, 8 waves (4Mw x 2Nw), wave 64x32 ============
// A LDS: [m][k] 256x64 bf16 SINGLE buffer via gload_lds (src pre-swizzled, read XOR (row&7)<<4).
// B LDS: [n][k] stride 72 shorts, XOR ((n>>2)&7)<<3. gateup: dbuf; down: single.
// 2 barriers/K-step; counted vmcnt; 2-deep B register prefetch.

// ---------------- Kernel 3: gate/up GEMM + SiLU -> hmid (bf16) ----------------
__global__ __launch_bounds__(512, 4) void gateup_kernel(
    const unsigned short* __restrict__ xb,
    const float* __restrict__ wg, const float* __restrict__ wu,
    const int* __restrict__ cnt, const int* __restrict__ tok_list,
    unsigned short* __restrict__ hmid)
{
  // bijective XCD-chunked swizzle: nwg=1536, q=192; same-expert blocks contiguous per XCD
  const int bid = blockIdx.x;
  const int wgid = (bid & 7) * 192 + (bid >> 3);
  const int e = wgid / 24, r24 = wgid % 24, nt = r24 >> 1, mt = r24 & 1;

  int ne = cnt[e]; ne = ne < CAPE ? ne : CAPE;
  if (mt * 256 >= ne) return;
  const int t = threadIdx.x, lane = t & 63, wid = t >> 6;
  const int wr = wid >> 1, wc = wid & 1;

  __shared__ __align__(16) unsigned short A[256 * 64];     // 32 KB single
  __shared__ __align__(16) unsigned short Bg[2 * 64 * 72]; // 18.4 KB dbuf
  __shared__ __align__(16) unsigned short Bu[2 * 64 * 72];
  __shared__ int toks[256];

  if (t < 256) {
    int rr = mt * 256 + t;
    toks[t] = tok_list[e * CAPE + (rr < ne ? rr : 0)];
  }
  __syncthreads();

  // A staging: 32 granule-insts of 1KB, 4 per wave
  const unsigned short* asrc[4];
  #pragma unroll
  for (int i = 0; i < 4; ++i) {
    const int inst = wid * 4 + i;
    const int G = inst * 64 + lane;
    const int m = G >> 3, gg = G & 7;
    asrc[i] = xb + (size_t)toks[m] * HD + 8 * (gg ^ (m & 7));
  }

  f32x4 z4 = {0.f, 0.f, 0.f, 0.f};
  f32x4 gacc[4][2], uacc[4][2];
  #pragma unroll
  for (int i = 0; i < 4; ++i)
    #pragma unroll
    for (int j = 0; j < 2; ++j) { gacc[i][j] = z4; uacc[i][j] = z4; }

  // B staging: waves 0-3 -> gate, waves 4-7 -> up
  const int bq = t & 255, nc = bq & 15, kc = bq >> 4;
  const float* wsel = (wid < 4) ? wg : wu;
  __bf16* bsel = (wid < 4) ? (__bf16*)Bg : (__bf16*)Bu;
  const size_t wbase = (size_t)e * HD * FD + (size_t)nt * 64;
  f32x4 Ra[4], Rb[4];

#define LOAD_GU(K0, R) do { \
    const float* p_ = wsel + wbase + (size_t)((K0) + kc * 4) * FD + nc * 4; \
    R[0] = *(const f32x4*)p_;            R[1] = *(const f32x4*)(p_ + FD); \
    R[2] = *(const f32x4*)(p_ + 2*FD);   R[3] = *(const f32x4*)(p_ + 3*FD); \
  } while (0)

#define STAGE_A(KT) do { \
    const int k0s_ = (KT) * 64; \
    _Pragma("unroll") \
    for (int i_ = 0; i_ < 4; ++i_) \
      load_lds16(asrc[i_] + k0s_, &A[(wid * 4 + i_) * 512]); \
  } while (0)

#define CVT_GU(BUF, R) do { \
    __bf16* b_ = bsel + (BUF) * 4608; \
    const int xm_ = (nc & 7) << 3; \
    _Pragma("unroll") \
    for (int j_ = 0; j_ < 4; ++j_) { \
      int so_ = (nc * 4 + j_) * 72 + ((kc * 4) ^ xm_); \
      *(bf16x4*)&b_[so_] = (bf16x4){(__bf16)R[0][j_], (__bf16)R[1][j_], (__bf16)R[2][j_], (__bf16)R[3][j_]}; \
    } \
  } while (0)

#define COMPUTE_GU(CUR) do { \
    const __bf16* Bg_ = (const __bf16*)&Bg[(CUR) * 4608]; \
    const __bf16* Bu_ = (const __bf16*)&Bu[(CUR) * 4608]; \
    _Pragma("unroll") \
    for (int ks = 0; ks < 2; ++ks) { \
      bf16x8 af[4]; \
      _Pragma("unroll") \
      for (int mf = 0; mf < 4; ++mf) { \
        int row = wr * 64 + mf * 16 + (lane & 15); \
        int byte = row * 128 + (lane >> 4) * 16 + ks * 64; \
        byte ^= (row & 7) << 4; \
        af[mf] = *(const bf16x8*)((const char*)A + byte); \
      } \
      _Pragma("unroll") \
      for (int nf = 0; nf < 2; ++nf) { \
        int n = wc * 32 + nf * 16 + (lane & 15); \
        int so = n * 72 + ((((lane >> 4) * 8) + ks * 32) ^ (((n >> 2) & 7) << 3)); \
        bf16x8 bgf = *(const bf16x8*)&Bg_[so]; \
        bf16x8 bum = *(const bf16x8*)&Bu_[so]; \
        _Pragma("unroll") \
        for (int mf = 0; mf < 4; ++mf) { \
          gacc[mf][nf] = __builtin_amdgcn_mfma_f32_16x16x32_bf16(af[mf], bgf, gacc[mf][nf], 0, 0, 0); \
          uacc[mf][nf] = __builtin_amdgcn_mfma_f32_16x16x32_bf16(af[mf], bum, uacc[mf][nf], 0, 0, 0); \
        } \
      } \
    } \
  } while (0)

  // prologue: tile0 -> A,B[0]; tile1 regs (Rb) in flight
  LOAD_GU(0, Ra);                            // +4
  PIN();
  STAGE_A(0);                                // +4 -> 8
  PIN();
  LOAD_GU(64, Rb);                           // +4 -> 12
  WAITCNT("s_waitcnt vmcnt(8)");             // Ra done
  CVT_GU(0, Ra);
  WAITCNT("s_waitcnt vmcnt(4) lgkmcnt(0)");  // A(0) staged; Rb flies
  BARRIER();

  // main: kt = 0..29 uniform; tiles 30,31 peeled
  for (int kt = 0; kt < 30; ++kt) {
    COMPUTE_GU(kt & 1);
    WAITCNT("s_waitcnt vmcnt(0)");           // B(kt+1) regs ready (long cover)
    if (kt & 1) CVT_GU((kt + 1) & 1, Ra); else CVT_GU((kt + 1) & 1, Rb);
    WAITCNT("s_waitcnt lgkmcnt(0)");
    BARRIER();                               // BAR1: A & B[cur] free
    STAGE_A(kt + 1);                         // +4
    PIN();
    if (kt & 1) LOAD_GU((kt + 2) * 64, Rb); else LOAD_GU((kt + 2) * 64, Ra);  // +4 -> 8
    WAITCNT("s_waitcnt vmcnt(4) lgkmcnt(0)");// A(kt+1) done; B(kt+2) flies
    BARRIER();                               // BAR2
  }
  // tail: tile 30 (buf 0), then 31
  COMPUTE_GU(0);
  WAITCNT("s_waitcnt vmcnt(0)");             // Rb (tile 31) ready
  CVT_GU(1, Rb);
  WAITCNT("s_waitcnt lgkmcnt(0)");
  BARRIER();
  STAGE_A(31);
  WAITCNT("s_waitcnt vmcnt(0) lgkmcnt(0)");
  BARRIER();
  COMPUTE_GU(1);

#undef LOAD_GU
#undef STAGE_A
#undef CVT_GU
#undef COMPUTE_GU

  // epilogue: hmid = silu(g)*u   (D layout: col=lane&15, row=4*(lane>>4)+reg)
  const size_t hbase = (size_t)e * CAPE + (size_t)mt * 256;
  __bf16* hm = (__bf16*)hmid;
  #pragma unroll
  for (int mf = 0; mf < 4; ++mf) {
    #pragma unroll
    for (int nf = 0; nf < 2; ++nf) {
      #pragma unroll
      for (int r = 0; r < 4; ++r) {
        int row = wr * 64 + mf * 16 + (lane >> 4) * 4 + r;
        int c = nt * 64 + wc * 32 + nf * 16 + (lane & 15);
        float gv = gacc[mf][nf][r], uv = uacc[mf][nf][r];
        float hv = gv / (1.f + __expf(-gv)) * uv;
        hm[(hbase + row) * FD + c] = (__bf16)hv;
      }
    }
  }
}

// ---------------- Kernel 4: down GEMM + weighted scatter-add ----------------
__global__ __launch_bounds__(512, 6) void down_kernel(
    const unsigned short* __restrict__ hmid,
    const float* __restrict__ wd,
    const int* __restrict__ cnt, const int* __restrict__ tok_list,
    const float* __restrict__ w_list, float* __restrict__ out)
{
  // nwg = 4096, q = 512
  const int bid = blockIdx.x;
  const int wgid = (bid & 7) * 512 + (bid >> 3);
  const int e = wgid / 64, r64 = wgid % 64, nt = r64 >> 1, mt = r64 & 1;

  int ne = cnt[e]; ne = ne < CAPE ? ne : CAPE;
  if (mt * 256 >= ne) return;
  const int t = threadIdx.x, lane = t & 63, wid = t >> 6;
  const int wr = wid >> 1, wc = wid & 1;

  __shared__ __align__(16) unsigned short A[256 * 64];   // 32 KB single
  __shared__ __align__(16) unsigned short Bd[64 * 72];   // 9.2 KB single
  __shared__ int toks[256];
  __shared__ float wts[256];

  if (t < 256) {
    int rr = mt * 256 + t;
    bool vv = rr < ne;
    toks[t] = vv ? tok_list[e * CAPE + rr] : 0;
    wts[t]  = vv ? w_list[e * CAPE + rr] : 0.f;
  }
  __syncthreads();

  const size_t arow = (size_t)e * CAPE + (size_t)mt * 256;
  const unsigned short* asrc[4];
  #pragma unroll
  for (int i = 0; i < 4; ++i) {
    const int inst = wid * 4 + i;
    const int G = inst * 64 + lane;
    const int m = G >> 3, gg = G & 7;
    asrc[i] = hmid + (arow + m) * FD + 8 * (gg ^ (m & 7));
  }

  f32x4 z4 = {0.f, 0.f, 0.f, 0.f};
  f32x4 dacc[4][2];
  #pragma unroll
  for (int i = 0; i < 4; ++i)
    #pragma unroll
    for (int j = 0; j < 2; ++j) dacc[i][j] = z4;

  // B staging: all 512 threads, 2 k-rows each
  const int nc = t & 15, kc2 = t >> 4;   // kc2: 0..31
  const size_t wbase = (size_t)e * FD * HD + (size_t)nt * 64;
  f32x4 Ra[2], Rb[2];

#define LOAD_D(K0, R) do { \
    const float* p_ = wd + wbase + (size_t)((K0) + kc2 * 2) * HD + nc * 4; \
    R[0] = *(const f32x4*)p_;  R[1] = *(const f32x4*)(p_ + HD); \
  } while (0)

#define STAGE_A(KT) do { \
    const int k0s_ = (KT) * 64; \
    _Pragma("unroll") \
    for (int i_ = 0; i_ < 4; ++i_) \
      load_lds16(asrc[i_] + k0s_, &A[(wid * 4 + i_) * 512]); \
  } while (0)

#define CVT_D(R) do { \
    __bf16* bd_ = (__bf16*)Bd; \
    const int xm_ = (nc & 7) << 3; \
    _Pragma("unroll") \
    for (int j_ = 0; j_ < 4; ++j_) { \
      int so_ = (nc * 4 + j_) * 72 + ((kc2 * 2) ^ xm_); \
      *(bf16x2*)&bd_[so_] = (bf16x2){(__bf16)R[0][j_], (__bf16)R[1][j_]}; \
    } \
  } while (0)

#define COMPUTE_D() do { \
    const __bf16* Bd_ = (const __bf16*)Bd; \
    _Pragma("unroll") \
    for (int ks = 0; ks < 2; ++ks) { \
      bf16x8 af[4]; \
      _Pragma("unroll") \
      for (int mf = 0; mf < 4; ++mf) { \
        int row = wr * 64 + mf * 16 + (lane & 15); \
        int byte = row * 128 + (lane >> 4) * 16 + ks * 64; \
        byte ^= (row & 7) << 4; \
        af[mf] = *(const bf16x8*)((const char*)A + byte); \
      } \
      _Pragma("unroll") \
      for (int nf = 0; nf < 2; ++nf) { \
        int n = wc * 32 + nf * 16 + (lane & 15); \
        int so = n * 72 + ((((lane >> 4) * 8) + ks * 32) ^ (((n >> 2) & 7) << 3)); \
        bf16x8 bdf = *(const bf16x8*)&Bd_[so]; \
        _Pragma("unroll") \
        for (int mf = 0; mf < 4; ++mf) \
          dacc[mf][nf] = __builtin_amdgcn_mfma_f32_16x16x32_bf16(af[mf], bdf, dacc[mf][nf], 0, 0, 0); \
      } \
    } \
  } while (0)

  // prologue
  LOAD_D(0, Ra);                             // +2
  PIN();
  STAGE_A(0);                                // +4 -> 6
  PIN();
  LOAD_D(64, Rb);                            // +2 -> 8
  WAITCNT("s_waitcnt vmcnt(6)");             // Ra done
  CVT_D(Ra);
  WAITCNT("s_waitcnt vmcnt(2) lgkmcnt(0)");  // A(0) staged; Rb flies
  BARRIER();

  // main: kt = 0..9 uniform; tiles 10,11 peeled
  for (int kt = 0; kt < 10; ++kt) {
    COMPUTE_D();                             // tile kt
    WAITCNT("s_waitcnt lgkmcnt(0)");
    BARRIER();                               // BAR1: A & Bd free
    WAITCNT("s_waitcnt vmcnt(0)");           // B(kt+1) regs ready
    if (kt & 1) CVT_D(Ra); else CVT_D(Rb);
    STAGE_A(kt + 1);                         // +4
    PIN();
    if (kt & 1) LOAD_D((kt + 2) * 64, Rb); else LOAD_D((kt + 2) * 64, Ra);  // +2 -> 6
    WAITCNT("s_waitcnt vmcnt(2) lgkmcnt(0)");// A done; new B flies; CVT writes drained
    BARRIER();                               // BAR2
  }
  // tail: tile 10, then 11
  COMPUTE_D();
  WAITCNT("s_waitcnt lgkmcnt(0)");
  BARRIER();
  WAITCNT("s_waitcnt vmcnt(0)");             // Rb (tile 11) ready
  CVT_D(Rb);
  STAGE_A(11);
  WAITCNT("s_waitcnt vmcnt(0) lgkmcnt(0)");
  BARRIER();
  COMPUTE_D();

#undef LOAD_D
#undef STAGE_A
#undef CVT_D
#undef COMPUTE_D

  // epilogue: weighted atomic scatter-add
  #pragma unroll
  for (int mf = 0; mf < 4; ++mf) {
    #pragma unroll
    for (int nf = 0; nf < 2; ++nf) {
      int c = nt * 64 + wc * 32 + nf * 16 + (lane & 15);
      #pragma unroll
      for (int r = 0; r < 4; ++r) {
        int row = wr * 64 + mf * 16 + (lane >> 4) * 4 + r;
        if (mt * 256 + row < ne) {
          int tok = toks[row];
          float w = wts[row];
          atomicAdd(&out[(size_t)tok * HD + c], w * dacc[mf][nf][r]);
        }
      }
    }
  }
}

extern "C" void kernel_launch(void* const* d_in, const int* in_sizes, int n_in,
                              void* d_out, int out_size, void* d_ws, size_t ws_size,
                              hipStream_t stream) {
  const float* x  = (const float*)d_in[0];
  const float* rw = (const float*)d_in[1];
  const float* wg = (const float*)d_in[2];
  const float* wu = (const float*)d_in[3];
  const float* wd = (const float*)d_in[4];
  float* out = (float*)d_out;

  char* ws = (char*)d_ws;
  unsigned short* xb   = (unsigned short*)ws;            // 8,388,608 B
  int* cnt             = (int*)(ws + 8388608);           // 256 B
  int* tok_list        = (int*)(ws + 8388864);           // 131,072 B
  float* w_list        = (float*)(ws + 8519936);         // 131,072 B
  unsigned short* hmid = (unsigned short*)(ws + 8651008);// 50,331,648 B

  hipMemsetAsync(d_out, 0, (size_t)out_size * sizeof(float), stream);
  hipMemsetAsync(cnt, 0, NEXP * sizeof(int), stream);

  router_kernel<<<T_TOK / 4, 256, 0, stream>>>(x, rw, cnt, tok_list, w_list, xb);
  gateup_kernel<<<1536, 512, 0, stream>>>(xb, wg, wu, cnt, tok_list, hmid);
  down_kernel<<<4096, 512, 0, stream>>>(hmid, wd, cnt, tok_list, w_list, out);
}

// Round 9
// 679.150 us; speedup vs baseline: 1.7790x; 1.7790x over previous
//
#include <hip/hip_runtime.h>
#include <math.h>

#define T_TOK 2048
#define HD    2048
#define NEXP  64
#define KTOP  8
#define FD    768
#define CAPE  512

typedef float  f32x4 __attribute__((ext_vector_type(4)));
typedef __bf16 bf16x8 __attribute__((ext_vector_type(8)));
typedef __bf16 bf16x4 __attribute__((ext_vector_type(4)));

__device__ __forceinline__ void load_lds16(const void* g, void* l) {
  __builtin_amdgcn_global_load_lds(
      (const __attribute__((address_space(1))) unsigned int*)g,
      (__attribute__((address_space(3))) unsigned int*)l, 16, 0, 0);
}

#define WAITCNT(S) asm volatile(S ::: "memory")
#define PIN()      asm volatile("" ::: "memory")
#define BARRIER()  __builtin_amdgcn_s_barrier()

// ---------------- Kernel 1: router (4 tokens per block) + fused f32->bf16 ----------------
__global__ __launch_bounds__(256) void router_kernel(
    const float* __restrict__ x, const float* __restrict__ rw,
    int* __restrict__ cnt, int* __restrict__ tok_list, float* __restrict__ w_list,
    unsigned short* __restrict__ xb)
{
  const int t = threadIdx.x;
  const int tb = blockIdx.x * 4;
  __shared__ float xs[4][HD];
  __shared__ float lg[4][NEXP];

  const float4* xsrc = (const float4*)(x + (size_t)tb * HD);
  float4* xdst = (float4*)&xs[0][0];
  for (int i = t; i < 4 * HD / 4; i += 256) xdst[i] = xsrc[i];
  __syncthreads();

  {
    const int e = t >> 2, q = t & 3;
    const float* wrow = rw + (size_t)e * HD;
    float a0 = 0.f, a1 = 0.f, a2 = 0.f, a3 = 0.f;
    for (int i = 0; i < HD / 16; ++i) {
      int h = (i * 4 + q) * 4;
      float4 wv = *(const float4*)(wrow + h);
      float4 x0 = *(const float4*)&xs[0][h];
      float4 x1 = *(const float4*)&xs[1][h];
      float4 x2 = *(const float4*)&xs[2][h];
      float4 x3 = *(const float4*)&xs[3][h];
      a0 += wv.x*x0.x + wv.y*x0.y + wv.z*x0.z + wv.w*x0.w;
      a1 += wv.x*x1.x + wv.y*x1.y + wv.z*x1.z + wv.w*x1.w;
      a2 += wv.x*x2.x + wv.y*x2.y + wv.z*x2.z + wv.w*x2.w;
      a3 += wv.x*x3.x + wv.y*x3.y + wv.z*x3.z + wv.w*x3.w;
    }
    a0 += __shfl_xor(a0, 1); a0 += __shfl_xor(a0, 2);
    a1 += __shfl_xor(a1, 1); a1 += __shfl_xor(a1, 2);
    a2 += __shfl_xor(a2, 1); a2 += __shfl_xor(a2, 2);
    a3 += __shfl_xor(a3, 1); a3 += __shfl_xor(a3, 2);
    if (q == 0) { lg[0][e] = a0; lg[1][e] = a1; lg[2][e] = a2; lg[3][e] = a3; }
  }

  {
    const f32x4* xs4 = (const f32x4*)(x + (size_t)tb * HD);
    bf16x4* xbd = (bf16x4*)(xb + (size_t)tb * HD);
    #pragma unroll
    for (int j = 0; j < 8; ++j) {
      f32x4 v = xs4[j * 256 + t];
      xbd[j * 256 + t] = (bf16x4){(__bf16)v[0], (__bf16)v[1], (__bf16)v[2], (__bf16)v[3]};
    }
  }
  __syncthreads();

  const int wid = t >> 6, lane = t & 63;
  float v = lg[wid][lane];
  float mx = v;
  for (int o = 32; o; o >>= 1) mx = fmaxf(mx, __shfl_xor(mx, o));
  float p = expf(v - mx);
  float s = p;
  for (int o = 32; o; o >>= 1) s += __shfl_xor(s, o);
  float prob = p / s;

  float r = prob;
  float wk[KTOP]; int ik[KTOP]; float wsum = 0.f;
  #pragma unroll
  for (int k = 0; k < KTOP; ++k) {
    float bv = r; int bl = lane;
    for (int o = 32; o; o >>= 1) {
      float ov = __shfl_xor(bv, o); int ol = __shfl_xor(bl, o);
      if (ov > bv || (ov == bv && ol < bl)) { bv = ov; bl = ol; }
    }
    wk[k] = bv; ik[k] = bl; wsum += bv;
    if (lane == bl) r = -1.f;
  }
  if (lane == 0) {
    float inv = 1.f / (wsum + 1e-20f);
    int token = tb + wid;
    #pragma unroll
    for (int k = 0; k < KTOP; ++k) {
      int ex = ik[k];
      int pos = atomicAdd(&cnt[ex], 1);
      if (pos < CAPE) {
        tok_list[ex * CAPE + pos] = token;
        w_list[ex * CAPE + pos] = wk[k] * inv;
      }
    }
  }
}

// ---------------- Kernel 3: gate/up GEMM + SiLU -> hmid (3-deep B prefetch) ----------------
__global__ __launch_bounds__(256, 2) void gateup_kernel(
    const unsigned short* __restrict__ xb,
    const float* __restrict__ wg, const float* __restrict__ wu,
    const int* __restrict__ cnt, const int* __restrict__ tok_list,
    unsigned short* __restrict__ hmid)
{
  const int nt = blockIdx.x, mt = blockIdx.y, e = blockIdx.z;
  int ne = cnt[e]; ne = ne < CAPE ? ne : CAPE;
  if (mt * 128 >= ne) return;
  const int t = threadIdx.x, lane = t & 63, wid = t >> 6;
  const int wr = wid >> 1, wc = wid & 1;

  __shared__ __align__(16) unsigned short A[2 * 128 * 64];
  __shared__ __align__(16) unsigned short Bg[2 * 64 * 72];
  __shared__ __align__(16) unsigned short Bu[2 * 64 * 72];
  __shared__ int toks[128];

  if (t < 128) {
    int r = mt * 128 + t;
    toks[t] = tok_list[e * CAPE + (r < ne ? r : 0)];
  }
  __syncthreads();

  const unsigned short* asrc[4];
  #pragma unroll
  for (int i = 0; i < 4; ++i) {
    const int inst = wid * 4 + i;
    const int G = inst * 64 + lane;
    const int m = G >> 3, gg = G & 7;
    asrc[i] = xb + (size_t)toks[m] * HD + 8 * (gg ^ (m & 7));
  }

  f32x4 z4 = {0.f, 0.f, 0.f, 0.f};
  f32x4 gacc[4][2], uacc[4][2];
  #pragma unroll
  for (int i = 0; i < 4; ++i)
    #pragma unroll
    for (int j = 0; j < 2; ++j) { gacc[i][j] = z4; uacc[i][j] = z4; }

  const size_t wbase = (size_t)e * HD * FD + (size_t)nt * 64;
  const int nc = t & 15, kc = t >> 4;
  f32x4 Ra[8], Rb[8], Rc[8];   // tile t lives in R[t % 3]

#define LOAD_GU(K0, R) do { \
    const float* pg_ = wg + wbase + (size_t)((K0) + kc * 4) * FD + nc * 4; \
    const float* pu_ = wu + wbase + (size_t)((K0) + kc * 4) * FD + nc * 4; \
    R[0] = *(const f32x4*)pg_;            R[1] = *(const f32x4*)(pg_ + FD); \
    R[2] = *(const f32x4*)(pg_ + 2*FD);   R[3] = *(const f32x4*)(pg_ + 3*FD); \
    R[4] = *(const f32x4*)pu_;            R[5] = *(const f32x4*)(pu_ + FD); \
    R[6] = *(const f32x4*)(pu_ + 2*FD);   R[7] = *(const f32x4*)(pu_ + 3*FD); \
  } while (0)

#define STAGE_A4(KT, BUF) do { \
    const int k0s_ = (KT) * 64; \
    _Pragma("unroll") \
    for (int i_ = 0; i_ < 4; ++i_) \
      load_lds16(asrc[i_] + k0s_, &A[(BUF) * 8192 + (wid * 4 + i_) * 512]); \
  } while (0)

#define CVT_GU(BUF, R) do { \
    __bf16* bg_ = (__bf16*)&Bg[(BUF) * 4608]; \
    __bf16* bu_ = (__bf16*)&Bu[(BUF) * 4608]; \
    const int xm_ = (nc & 7) << 3; \
    _Pragma("unroll") \
    for (int j_ = 0; j_ < 4; ++j_) { \
      int so_ = (nc * 4 + j_) * 72 + ((kc * 4) ^ xm_); \
      *(bf16x4*)&bg_[so_] = (bf16x4){(__bf16)R[0][j_], (__bf16)R[1][j_], (__bf16)R[2][j_], (__bf16)R[3][j_]}; \
      *(bf16x4*)&bu_[so_] = (bf16x4){(__bf16)R[4][j_], (__bf16)R[5][j_], (__bf16)R[6][j_], (__bf16)R[7][j_]}; \
    } \
  } while (0)

#define COMPUTE_GU(CUR) do { \
    const char* Ab_ = (const char*)&A[(CUR) * 8192]; \
    const __bf16* Bg_ = (const __bf16*)&Bg[(CUR) * 4608]; \
    const __bf16* Bu_ = (const __bf16*)&Bu[(CUR) * 4608]; \
    _Pragma("unroll") \
    for (int ks = 0; ks < 2; ++ks) { \
      bf16x8 af[4]; \
      _Pragma("unroll") \
      for (int mf = 0; mf < 4; ++mf) { \
        int row = wr * 64 + mf * 16 + (lane & 15); \
        int byte = row * 128 + (lane >> 4) * 16 + ks * 64; \
        byte ^= (row & 7) << 4; \
        af[mf] = *(const bf16x8*)(Ab_ + byte); \
      } \
      _Pragma("unroll") \
      for (int nf = 0; nf < 2; ++nf) { \
        int n = wc * 32 + nf * 16 + (lane & 15); \
        int so = n * 72 + ((((lane >> 4) * 8) + ks * 32) ^ (((n >> 2) & 7) << 3)); \
        bf16x8 bgf = *(const bf16x8*)&Bg_[so]; \
        bf16x8 bum = *(const bf16x8*)&Bu_[so]; \
        _Pragma("unroll") \
        for (int mf = 0; mf < 4; ++mf) { \
          gacc[mf][nf] = __builtin_amdgcn_mfma_f32_16x16x32_bf16(af[mf], bgf, gacc[mf][nf], 0, 0, 0); \
          uacc[mf][nf] = __builtin_amdgcn_mfma_f32_16x16x32_bf16(af[mf], bum, uacc[mf][nf], 0, 0, 0); \
        } \
      } \
    } \
  } while (0)

// one steady-state K-step: stage A(kt+1), load B(kt+3), cvt B(kt+1), compute kt
#define STEP_GU(KT, RCVT, RLOAD) do { \
    STAGE_A4((KT) + 1, ((KT) + 1) & 1);  PIN(); \
    LOAD_GU(((KT) + 3) * 64, RLOAD);     PIN(); \
    WAITCNT("s_waitcnt vmcnt(20)"); \
    CVT_GU(((KT) + 1) & 1, RCVT); \
    COMPUTE_GU((KT) & 1); \
    WAITCNT("s_waitcnt vmcnt(16) lgkmcnt(0)"); \
    BARRIER(); \
  } while (0)

  // prologue: tiles 0,1,2 in flight
  LOAD_GU(0, Ra);            PIN();   // 8
  STAGE_A4(0, 0);            PIN();   // 12
  LOAD_GU(64, Rb);           PIN();   // 20
  LOAD_GU(128, Rc);          PIN();   // 28
  WAITCNT("s_waitcnt vmcnt(20)");             // Ra done
  CVT_GU(0, Ra);
  WAITCNT("s_waitcnt vmcnt(16) lgkmcnt(0)");  // A(0) done; Rb,Rc fly
  BARRIER();

  // main: 9 triples = kt 0..26 (loads tiles 3..29)
  for (int i = 0; i < 9; ++i) {
    const int kt = 3 * i;
    STEP_GU(kt + 0, Rb, Ra);
    STEP_GU(kt + 1, Rc, Rb);
    STEP_GU(kt + 2, Ra, Rc);
  }
  // kt=27 (load tile 30 -> Ra), kt=28 (load 31 -> Rb)
  STEP_GU(27, Rb, Ra);
  STEP_GU(28, Rc, Rb);
  // kt=29: no load. outstanding [B30:8, B31:8]
  STAGE_A4(30, 0);  PIN();                     // +4 -> 20
  WAITCNT("s_waitcnt vmcnt(12)");              // B30 (Ra) done
  CVT_GU(0, Ra);
  COMPUTE_GU(1);                               // tile 29
  WAITCNT("s_waitcnt vmcnt(0) lgkmcnt(0)");    // A(30) done (drains B31 too)
  BARRIER();
  // kt=30
  STAGE_A4(31, 1);  PIN();
  CVT_GU(1, Rb);                               // tile 31 (already drained)
  COMPUTE_GU(0);                               // tile 30
  WAITCNT("s_waitcnt vmcnt(0) lgkmcnt(0)");
  BARRIER();
  COMPUTE_GU(1);                               // tile 31

#undef LOAD_GU
#undef STAGE_A4
#undef CVT_GU
#undef COMPUTE_GU
#undef STEP_GU

  const size_t hbase = (size_t)e * CAPE + (size_t)mt * 128;
  __bf16* hm = (__bf16*)hmid;
  #pragma unroll
  for (int mf = 0; mf < 4; ++mf) {
    #pragma unroll
    for (int nf = 0; nf < 2; ++nf) {
      #pragma unroll
      for (int r = 0; r < 4; ++r) {
        int row = wr * 64 + mf * 16 + (lane >> 4) * 4 + r;
        int c = nt * 64 + wc * 32 + nf * 16 + (lane & 15);
        float gv = gacc[mf][nf][r], uv = uacc[mf][nf][r];
        float hv = gv / (1.f + __expf(-gv)) * uv;
        hm[(hbase + row) * FD + c] = (__bf16)hv;
      }
    }
  }
}

// ---------------- Kernel 4: down GEMM + weighted scatter-add (3-deep B prefetch) ----------------
__global__ __launch_bounds__(256, 2) void down_kernel(
    const unsigned short* __restrict__ hmid,
    const float* __restrict__ wd,
    const int* __restrict__ cnt, const int* __restrict__ tok_list,
    const float* __restrict__ w_list, float* __restrict__ out)
{
  const int nt = blockIdx.x, mt = blockIdx.y, e = blockIdx.z;
  int ne = cnt[e]; ne = ne < CAPE ? ne : CAPE;
  if (mt * 128 >= ne) return;
  const int t = threadIdx.x, lane = t & 63, wid = t >> 6;
  const int wr = wid >> 1, wc = wid & 1;

  __shared__ __align__(16) unsigned short A[2 * 128 * 64];
  __shared__ __align__(16) unsigned short Bd[2 * 64 * 72];
  __shared__ int toks[128];
  __shared__ float wts[128];

  if (t < 128) {
    int r = mt * 128 + t;
    bool vv = r < ne;
    toks[t] = vv ? tok_list[e * CAPE + r] : 0;
    wts[t]  = vv ? w_list[e * CAPE + r] : 0.f;
  }
  __syncthreads();

  const size_t arow = (size_t)e * CAPE + (size_t)mt * 128;
  const unsigned short* asrc[4];
  #pragma unroll
  for (int i = 0; i < 4; ++i) {
    const int inst = wid * 4 + i;
    const int G = inst * 64 + lane;
    const int m = G >> 3, gg = G & 7;
    asrc[i] = hmid + (arow + m) * FD + 8 * (gg ^ (m & 7));
  }

  f32x4 z4 = {0.f, 0.f, 0.f, 0.f};
  f32x4 dacc[4][2];
  #pragma unroll
  for (int i = 0; i < 4; ++i)
    #pragma unroll
    for (int j = 0; j < 2; ++j) dacc[i][j] = z4;

  const size_t wbase = (size_t)e * FD * HD + (size_t)nt * 64;
  const int nc = t & 15, kc = t >> 4;
  f32x4 Ra[4], Rb[4], Rc[4];   // tile t in R[t % 3]

#define LOAD_D(K0, R) do { \
    const float* pd_ = wd + wbase + (size_t)((K0) + kc * 4) * HD + nc * 4; \
    R[0] = *(const f32x4*)pd_;            R[1] = *(const f32x4*)(pd_ + HD); \
    R[2] = *(const f32x4*)(pd_ + 2*HD);   R[3] = *(const f32x4*)(pd_ + 3*HD); \
  } while (0)

#define STAGE_A4(KT, BUF) do { \
    const int k0s_ = (KT) * 64; \
    _Pragma("unroll") \
    for (int i_ = 0; i_ < 4; ++i_) \
      load_lds16(asrc[i_] + k0s_, &A[(BUF) * 8192 + (wid * 4 + i_) * 512]); \
  } while (0)

#define CVT_D(BUF, R) do { \
    __bf16* bd_ = (__bf16*)&Bd[(BUF) * 4608]; \
    const int xm_ = (nc & 7) << 3; \
    _Pragma("unroll") \
    for (int j_ = 0; j_ < 4; ++j_) { \
      int so_ = (nc * 4 + j_) * 72 + ((kc * 4) ^ xm_); \
      *(bf16x4*)&bd_[so_] = (bf16x4){(__bf16)R[0][j_], (__bf16)R[1][j_], (__bf16)R[2][j_], (__bf16)R[3][j_]}; \
    } \
  } while (0)

#define COMPUTE_D(CUR) do { \
    const char* Ab_ = (const char*)&A[(CUR) * 8192]; \
    const __bf16* Bd_ = (const __bf16*)&Bd[(CUR) * 4608]; \
    _Pragma("unroll") \
    for (int ks = 0; ks < 2; ++ks) { \
      bf16x8 af[4]; \
      _Pragma("unroll") \
      for (int mf = 0; mf < 4; ++mf) { \
        int row = wr * 64 + mf * 16 + (lane & 15); \
        int byte = row * 128 + (lane >> 4) * 16 + ks * 64; \
        byte ^= (row & 7) << 4; \
        af[mf] = *(const bf16x8*)(Ab_ + byte); \
      } \
      _Pragma("unroll") \
      for (int nf = 0; nf < 2; ++nf) { \
        int n = wc * 32 + nf * 16 + (lane & 15); \
        int so = n * 72 + ((((lane >> 4) * 8) + ks * 32) ^ (((n >> 2) & 7) << 3)); \
        bf16x8 bdf = *(const bf16x8*)&Bd_[so]; \
        _Pragma("unroll") \
        for (int mf = 0; mf < 4; ++mf) \
          dacc[mf][nf] = __builtin_amdgcn_mfma_f32_16x16x32_bf16(af[mf], bdf, dacc[mf][nf], 0, 0, 0); \
      } \
    } \
  } while (0)

#define STEP_D(KT, RCVT, RLOAD) do { \
    STAGE_A4((KT) + 1, ((KT) + 1) & 1);  PIN(); \
    LOAD_D(((KT) + 3) * 64, RLOAD);      PIN(); \
    WAITCNT("s_waitcnt vmcnt(12)"); \
    CVT_D(((KT) + 1) & 1, RCVT); \
    COMPUTE_D((KT) & 1); \
    WAITCNT("s_waitcnt vmcnt(8) lgkmcnt(0)"); \
    BARRIER(); \
  } while (0)

  // prologue: tiles 0,1,2
  LOAD_D(0, Ra);            PIN();   // 4
  STAGE_A4(0, 0);           PIN();   // 8
  LOAD_D(64, Rb);           PIN();   // 12
  LOAD_D(128, Rc);          PIN();   // 16
  WAITCNT("s_waitcnt vmcnt(12)");             // Ra done
  CVT_D(0, Ra);
  WAITCNT("s_waitcnt vmcnt(8) lgkmcnt(0)");   // A(0) done
  BARRIER();

  // main: 3 triples = kt 0..8 (loads tiles 3..11)
  for (int i = 0; i < 3; ++i) {
    const int kt = 3 * i;
    STEP_D(kt + 0, Rb, Ra);
    STEP_D(kt + 1, Rc, Rb);
    STEP_D(kt + 2, Ra, Rc);
  }
  // kt=9: no load. outstanding [B10:4, B11:4]
  STAGE_A4(10, 0);  PIN();                    // +4 -> 12
  WAITCNT("s_waitcnt vmcnt(8)");              // B10 (Rb) done
  CVT_D(0, Rb);
  COMPUTE_D(1);                               // tile 9
  WAITCNT("s_waitcnt vmcnt(0) lgkmcnt(0)");   // A(10) done
  BARRIER();
  // kt=10
  STAGE_A4(11, 1);  PIN();
  CVT_D(1, Rc);                               // tile 11
  COMPUTE_D(0);                               // tile 10
  WAITCNT("s_waitcnt vmcnt(0) lgkmcnt(0)");
  BARRIER();
  COMPUTE_D(1);                               // tile 11

#undef LOAD_D
#undef STAGE_A4
#undef CVT_D
#undef COMPUTE_D
#undef STEP_D

  #pragma unroll
  for (int mf = 0; mf < 4; ++mf) {
    #pragma unroll
    for (int nf = 0; nf < 2; ++nf) {
      int c = nt * 64 + wc * 32 + nf * 16 + (lane & 15);
      #pragma unroll
      for (int r = 0; r < 4; ++r) {
        int row = wr * 64 + mf * 16 + (lane >> 4) * 4 + r;
        if (mt * 128 + row < ne) {
          int tok = toks[row];
          float w = wts[row];
          atomicAdd(&out[(size_t)tok * HD + c], w * dacc[mf][nf][r]);
        }
      }
    }
  }
}

extern "C" void kernel_launch(void* const* d_in, const int* in_sizes, int n_in,
                              void* d_out, int out_size, void* d_ws, size_t ws_size,
                              hipStream_t stream) {
  const float* x  = (const float*)d_in[0];
  const float* rw = (const float*)d_in[1];
  const float* wg = (const float*)d_in[2];
  const float* wu = (const float*)d_in[3];
  const float* wd = (const float*)d_in[4];
  float* out = (float*)d_out;

  char* ws = (char*)d_ws;
  unsigned short* xb   = (unsigned short*)ws;            // 8,388,608 B
  int* cnt             = (int*)(ws + 8388608);           // 256 B
  int* tok_list        = (int*)(ws + 8388864);           // 131,072 B
  float* w_list        = (float*)(ws + 8519936);         // 131,072 B
  unsigned short* hmid = (unsigned short*)(ws + 8651008);// 50,331,648 B

  hipMemsetAsync(d_out, 0, (size_t)out_size * sizeof(float), stream);
  hipMemsetAsync(cnt, 0, NEXP * sizeof(int), stream);

  router_kernel<<<T_TOK / 4, 256, 0, stream>>>(x, rw, cnt, tok_list, w_list, xb);
  gateup_kernel<<<dim3(FD / 64, CAPE / 128, NEXP), 256, 0, stream>>>(xb, wg, wu, cnt, tok_list, hmid);
  down_kernel<<<dim3(HD / 64, CAPE / 128, NEXP), 256, 0, stream>>>(hmid, wd, cnt, tok_list, w_list, out);
}